// Round 4
// baseline (276.361 us; speedup 1.0000x reference)
//
#include <hip/hip_runtime.h>
#include <stdint.h>

using f16 = _Float16;

typedef _Float16 f16x8 __attribute__((ext_vector_type(8)));
typedef float f32x4 __attribute__((ext_vector_type(4)));

#define LOG2E 1.44269504088896340736f

__device__ __forceinline__ f16 f2h(float f) { return (f16)f; }  // RNE

#if __has_builtin(__builtin_amdgcn_exp2f)
__device__ __forceinline__ float fexp2(float x) { return __builtin_amdgcn_exp2f(x); }
#else
__device__ __forceinline__ float fexp2(float x) { return exp2f(x); }
#endif

__device__ __forceinline__ f16x8 cvt8(const float* p) {
  const float4 a = *(const float4*)p;
  const float4 b = *(const float4*)(p + 4);
  f16x8 r;
  r[0] = (f16)a.x; r[1] = (f16)a.y; r[2] = (f16)a.z; r[3] = (f16)a.w;
  r[4] = (f16)b.x; r[5] = (f16)b.y; r[6] = (f16)b.z; r[7] = (f16)b.w;
  return r;
}

// B=4, C=64, N=4096.  Global in/out tensors FP32; internal tensor-core path FP16.
// ws layout (bytes):
//   0        qa  f16 [4][4096][64]  (2 MB)   q * log2e, position-major
//   2 MB     ka  f16 [4][4096][64]  (2 MB)
//   4 MB     va  f16 [4][64][4096]  (2 MB)   channel-major
//   6 MB     y0  f32 [4][64][4096]  (4 MB)   gamma*attn_out, pre-BN
//   10 MB    stats: gs1[64] | gs2[64] | par float2[64]

// ---------------------------------------------------------------------------
// pre: conv1d q/k over channels, v = vw@x+vb via MFMA
// grid 256 = (b, n-tile of 64), 256 threads
// ---------------------------------------------------------------------------
__global__ __launch_bounds__(256, 1) void pam_pre(
    const float* __restrict__ x, const float* __restrict__ qw,
    const float* __restrict__ kw, const float* __restrict__ vw,
    const float* __restrict__ vb,
    f16* __restrict__ qa, f16* __restrict__ ka, f16* __restrict__ va)
{
  __shared__ alignas(16) f16 xt[64 * 72];   // xt[n][c] f16, row stride 72 elems
  const int tid = threadIdx.x;
  const int b = blockIdx.x >> 6;
  const int n0 = (blockIdx.x & 63) << 6;
  const int lane = tid & 63;
  const int wv = tid >> 6;
  const int quad = lane >> 4, l15 = lane & 15;

  // stage x[b][c][n0:+64] (fp32) transposed into xt[n][c] (f16)
  for (int p = 0; p < 4; ++p) {
    const int c = p * 16 + (tid >> 4);
    const int j0 = (tid & 15) << 2;
    const float4 v4 = *(const float4*)(x + ((size_t)(b * 64 + c) << 12) + n0 + j0);
    xt[(j0 + 0) * 72 + c] = f2h(v4.x);
    xt[(j0 + 1) * 72 + c] = f2h(v4.y);
    xt[(j0 + 2) * 72 + c] = f2h(v4.z);
    xt[(j0 + 3) * 72 + c] = f2h(v4.w);
  }
  __syncthreads();

  // conv along channel axis (SAME, zero pad), fp32 math on f16-rounded x
  const float qw0 = qw[0], qw1 = qw[1], qw2 = qw[2];
  const float kw0 = kw[0], kw1 = kw[1], kw2 = kw[2];
  for (int p = 0; p < 16; ++p) {
    const int c = lane;
    const int jr = (p << 2) + wv;
    const int n = n0 + jr;
    const float xm = (c > 0) ? (float)xt[jr * 72 + c - 1] : 0.f;
    const float x0 = (float)xt[jr * 72 + c];
    const float xp = (c < 63) ? (float)xt[jr * 72 + c + 1] : 0.f;
    const float qv = (qw0 * xm + qw1 * x0 + qw2 * xp) * LOG2E;  // log2-domain
    const float kv = kw0 * xm + kw1 * x0 + kw2 * xp;
    const size_t off = ((size_t)((b << 12) + n) << 6) + c;
    qa[off] = f2h(qv);
    ka[off] = f2h(kv);
  }

  // v[b][c][n] = vw @ x + vb via mfma 16x16x32 (wave wv -> c rows [16wv,+16))
  {
    const f16x8 a0 = cvt8(vw + (wv * 16 + l15) * 64 + quad * 8);
    const f16x8 a1 = cvt8(vw + (wv * 16 + l15) * 64 + quad * 8 + 32);
    f32x4 acc[4];
    for (int st = 0; st < 4; ++st) {
      const f16x8 b0 = *(const f16x8*)&xt[(st * 16 + l15) * 72 + quad * 8];
      const f16x8 b1 = *(const f16x8*)&xt[(st * 16 + l15) * 72 + quad * 8 + 32];
      f32x4 z = {0.f, 0.f, 0.f, 0.f};
      z = __builtin_amdgcn_mfma_f32_16x16x32_f16(a0, b0, z, 0, 0, 0);
      acc[st] = __builtin_amdgcn_mfma_f32_16x16x32_f16(a1, b1, z, 0, 0, 0);
    }
    const int cobase = wv * 16 + quad * 4;
    for (int st = 0; st < 4; ++st)
      for (int r = 0; r < 4; ++r) {
        const int co = cobase + r;
        const float val = acc[st][r] + vb[co];
        va[((size_t)(b * 64 + co) << 12) + n0 + st * 16 + l15] = f2h(val);
      }
  }
}

// ---------------------------------------------------------------------------
// attention: block = (b, 64 queries); 4 waves key-split (32 keys each, KT=128)
// pass 1: exact per-query row max (GEMM1 only).  pass 2: exact softmax + PV.
// grid 256, 256 threads.  b = bx&3 -> one batch per XCD (L2 locality).
// ---------------------------------------------------------------------------
__global__ __launch_bounds__(256, 1) void pam_attn(
    const f16* __restrict__ qa, const f16* __restrict__ ka,
    const f16* __restrict__ va, const float* __restrict__ gam,
    float* __restrict__ y0, float* __restrict__ gs1, float* __restrict__ gs2)
{
  __shared__ alignas(16) f16 pbuf[4][64 * 32];  // per-wave P [q][key], 64B rows, 16B-chunk xor swizzle
  __shared__ float ldsO[64 * 65];
  __shared__ float ldsL[4][64];
  __shared__ float ldsM[4][64];
  __shared__ float ldsInv[64];

  const int tid = threadIdx.x;
  const int wv = tid >> 6, lane = tid & 63;
  const int quad = lane >> 4, l15 = lane & 15;
  const int b = blockIdx.x & 3;
  const int qb0 = (blockIdx.x >> 2) << 6;

  for (int i = tid; i < 64 * 65; i += 256) ldsO[i] = 0.f;

  const int bn = b << 12;
  f16x8 bq[4][2];
  for (int qt = 0; qt < 4; ++qt) {
    const int q = qb0 + qt * 16 + l15;
    const f16* qp = qa + ((size_t)(bn + q) << 6) + quad * 8;
    bq[qt][0] = *(const f16x8*)qp;
    bq[qt][1] = *(const f16x8*)(qp + 32);
  }

  // ---- pass 1: exact row max over this wave's 1024 keys, then merge ----
  float rmax[4] = {-3e38f, -3e38f, -3e38f, -3e38f};
  {
    f16x8 k0[2][2], k1[2][2];
    for (int mt = 0; mt < 2; ++mt) {
      const f16* kp = ka + ((size_t)(bn + wv * 32 + mt * 16 + l15) << 6) + quad * 8;
      k0[mt][0] = *(const f16x8*)kp;
      k0[mt][1] = *(const f16x8*)(kp + 32);
    }
#pragma unroll 2
    for (int kt = 0; kt < 32; ++kt) {
      const int kb2 = ((kt < 31) ? kt + 1 : 31) * 128 + wv * 32;
      for (int mt = 0; mt < 2; ++mt) {
        const f16* kp = ka + ((size_t)(bn + kb2 + mt * 16 + l15) << 6) + quad * 8;
        k1[mt][0] = *(const f16x8*)kp;
        k1[mt][1] = *(const f16x8*)(kp + 32);
      }
      for (int mt = 0; mt < 2; ++mt)
        for (int qt = 0; qt < 4; ++qt) {
          f32x4 z = {0.f, 0.f, 0.f, 0.f};
          z = __builtin_amdgcn_mfma_f32_16x16x32_f16(k0[mt][0], bq[qt][0], z, 0, 0, 0);
          z = __builtin_amdgcn_mfma_f32_16x16x32_f16(k0[mt][1], bq[qt][1], z, 0, 0, 0);
          rmax[qt] = fmaxf(rmax[qt],
                           fmaxf(fmaxf(z[0], z[1]), fmaxf(z[2], z[3])));
        }
      for (int mt = 0; mt < 2; ++mt) { k0[mt][0] = k1[mt][0]; k0[mt][1] = k1[mt][1]; }
    }
  }
  for (int qt = 0; qt < 4; ++qt) {
    float v = rmax[qt];
    v = fmaxf(v, __shfl_xor(v, 16, 64));
    v = fmaxf(v, __shfl_xor(v, 32, 64));
    rmax[qt] = v;
  }
  if (quad == 0)
    for (int qt = 0; qt < 4; ++qt) ldsM[wv][qt * 16 + l15] = rmax[qt];

  __syncthreads();  // ldsM published; ldsO zero-init done

  float Mcol[4];
  for (int qt = 0; qt < 4; ++qt) {
    const int q = qt * 16 + l15;
    Mcol[qt] = fmaxf(fmaxf(ldsM[0][q], ldsM[1][q]), fmaxf(ldsM[2][q], ldsM[3][q]));
  }

  f32x4 o[4][4] = {};
  float lpart[4] = {0.f, 0.f, 0.f, 0.f};
  f16* pb = pbuf[wv];

  // preload iteration 0 K/V fragments
  f16x8 ak[2][2], bv[4];
  {
    const int kb = wv * 32;
    for (int mt = 0; mt < 2; ++mt) {
      const f16* kp = ka + ((size_t)(bn + kb + mt * 16 + l15) << 6) + quad * 8;
      ak[mt][0] = *(const f16x8*)kp;
      ak[mt][1] = *(const f16x8*)(kp + 32);
    }
    for (int ct = 0; ct < 4; ++ct)
      bv[ct] = *(const f16x8*)(va + ((size_t)(b * 64 + ct * 16 + l15) << 12) + kb + quad * 8);
  }

#pragma unroll 2
  for (int kt = 0; kt < 32; ++kt) {
    // S^T = K_slice * Q^T, with C preloaded to -M (exact softmax shift)
    f32x4 s[2][4];
    for (int mt = 0; mt < 2; ++mt)
      for (int qt = 0; qt < 4; ++qt) {
        f32x4 z = {-Mcol[qt], -Mcol[qt], -Mcol[qt], -Mcol[qt]};
        z = __builtin_amdgcn_mfma_f32_16x16x32_f16(ak[mt][0], bq[qt][0], z, 0, 0, 0);
        s[mt][qt] = __builtin_amdgcn_mfma_f32_16x16x32_f16(ak[mt][1], bq[qt][1], z, 0, 0, 0);
      }

    // prefetch next iteration's K/V (overlaps softmax + GEMM2)
    f16x8 akn[2][2], bvn[4];
    {
      const int kb2 = ((kt < 31) ? kt + 1 : 31) * 128 + wv * 32;
      for (int mt = 0; mt < 2; ++mt) {
        const f16* kp = ka + ((size_t)(bn + kb2 + mt * 16 + l15) << 6) + quad * 8;
        akn[mt][0] = *(const f16x8*)kp;
        akn[mt][1] = *(const f16x8*)(kp + 32);
      }
      for (int ct = 0; ct < 4; ++ct)
        bvn[ct] = *(const f16x8*)(va + ((size_t)(b * 64 + ct * 16 + l15) << 12) + kb2 + quad * 8);
    }

    // P = exp2(S - M); accumulate l; pack 4 consecutive keys -> b64 LDS write
    for (int qt = 0; qt < 4; ++qt) {
      const int rowq = qt * 16 + l15;
      char* rowp = (char*)pb + rowq * 64;
      const int sw = rowq & 3;
      for (int mt = 0; mt < 2; ++mt) {
        const float p0 = fexp2(s[mt][qt][0]);
        const float p1 = fexp2(s[mt][qt][1]);
        const float p2 = fexp2(s[mt][qt][2]);
        const float p3 = fexp2(s[mt][qt][3]);
        lpart[qt] += (p0 + p1) + (p2 + p3);
        union { f16 h[4]; uint2 u; } pk;
        pk.h[0] = f2h(p0); pk.h[1] = f2h(p1);
        pk.h[2] = f2h(p2); pk.h[3] = f2h(p3);
        const int cc = (2 * mt + (quad >> 1)) ^ sw;          // swizzled 16B-chunk pos
        *(uint2*)(rowp + cc * 16 + (quad & 1) * 8) = pk.u;
      }
    }
    __builtin_amdgcn_s_waitcnt(0xC07F);  // lgkmcnt(0): per-wave P writes visible

    // O[q][c] += P * V  (A = P from LDS, B = V channel-major, K = 32 keys)
    for (int qt = 0; qt < 4; ++qt) {
      const int rowq = qt * 16 + l15;
      const f16x8 ap =
          *(const f16x8*)((const char*)pb + rowq * 64 + ((quad ^ (rowq & 3)) << 4));
      for (int ct = 0; ct < 4; ++ct)
        o[qt][ct] = __builtin_amdgcn_mfma_f32_16x16x32_f16(ap, bv[ct], o[qt][ct], 0, 0, 0);
    }

    for (int mt = 0; mt < 2; ++mt) { ak[mt][0] = akn[mt][0]; ak[mt][1] = akn[mt][1]; }
    for (int ct = 0; ct < 4; ++ct) bv[ct] = bvn[ct];
  }

  // l: reduce across quads (rows of S^T live across quads), publish per wave
  for (int qt = 0; qt < 4; ++qt) {
    float v = lpart[qt];
    v += __shfl_xor(v, 16, 64);
    v += __shfl_xor(v, 32, 64);
    lpart[qt] = v;
  }
  if (quad == 0)
    for (int qt = 0; qt < 4; ++qt) ldsL[wv][qt * 16 + l15] = lpart[qt];

  // merge partial O across the 4 key-split waves
  for (int qt = 0; qt < 4; ++qt) {
    const int row = qt * 16 + quad * 4;
    for (int ct = 0; ct < 4; ++ct) {
      const int col = ct * 16 + l15;
      for (int r = 0; r < 4; ++r)
        atomicAdd(&ldsO[(row + r) * 65 + col], o[qt][ct][r]);
    }
  }
  __syncthreads();
  if (tid < 64)
    ldsInv[tid] = 1.f / (ldsL[0][tid] + ldsL[1][tid] + ldsL[2][tid] + ldsL[3][tid]);
  __syncthreads();

  // epilogue: y0[b][c][n] = gamma * O / l ; BN partial sums
  const float g = gam[0];
  for (int p = 0; p < 16; ++p) {
    const int c = (p << 2) + wv;
    const float val = g * ldsO[lane * 65 + c] * ldsInv[lane];
    y0[((size_t)(b * 64 + c) << 12) + qb0 + lane] = val;
    float s1 = val, s2 = val * val;
    for (int m = 1; m < 64; m <<= 1) {
      s1 += __shfl_xor(s1, m, 64);
      s2 += __shfl_xor(s2, m, 64);
    }
    if (lane == 0) { atomicAdd(&gs1[c], s1); atomicAdd(&gs2[c], s2); }
  }
}

// ---------------------------------------------------------------------------
__global__ __launch_bounds__(64, 1) void pam_stats(
    const float* __restrict__ gs1, const float* __restrict__ gs2,
    const float* __restrict__ bnw, const float* __restrict__ bnb,
    float2* __restrict__ par)
{
  const int c = threadIdx.x;
  const float inv_n = 1.f / 16384.f;
  const float mean = gs1[c] * inv_n;
  const float var = fmaxf(gs2[c] * inv_n - mean * mean, 0.f);
  const float sc = bnw[c] * rsqrtf(var + 1e-5f);
  par[c] = make_float2(sc, bnb[c] - mean * sc);
}

// ---------------------------------------------------------------------------
__global__ __launch_bounds__(256, 1) void pam_apply(
    const float* __restrict__ y0, const float* __restrict__ x,
    const float2* __restrict__ par, float* __restrict__ out)
{
  const int i = (blockIdx.x * 256 + threadIdx.x) << 2;   // 4 elems/thread, exact cover
  const int c = (i >> 12) & 63;
  const float2 p = par[c];
  const float4 y = *(const float4*)(y0 + i);
  const float4 xv = *(const float4*)(x + i);
  float4 r;
  r.x = y.x * p.x + p.y + xv.x;
  r.y = y.y * p.x + p.y + xv.y;
  r.z = y.z * p.x + p.y + xv.z;
  r.w = y.w * p.x + p.y + xv.w;
  *(float4*)(out + i) = r;
}

// ---------------------------------------------------------------------------
extern "C" void kernel_launch(void* const* d_in, const int* in_sizes, int n_in,
                              void* d_out, int out_size, void* d_ws, size_t ws_size,
                              hipStream_t stream)
{
  (void)in_sizes; (void)n_in; (void)out_size; (void)ws_size;
  const float* x   = (const float*)d_in[0];
  const float* qw  = (const float*)d_in[1];
  const float* kw  = (const float*)d_in[2];
  const float* vw  = (const float*)d_in[3];
  const float* vb  = (const float*)d_in[4];
  const float* gam = (const float*)d_in[5];
  const float* bnw = (const float*)d_in[6];
  const float* bnb = (const float*)d_in[7];

  char* ws = (char*)d_ws;
  f16*   qa  = (f16*)(ws);
  f16*   ka  = (f16*)(ws + (2u << 20));
  f16*   va  = (f16*)(ws + (4u << 20));
  float* y0  = (float*)(ws + (6u << 20));
  char*  st  = ws + (10u << 20);
  float*  gs1  = (float*)(st);           // 64 floats
  float*  gs2  = (float*)(st + 256);     // 64 floats
  float2* par  = (float2*)(st + 512);    // 64 float2

  hipMemsetAsync(st, 0, 512, stream);
  pam_pre  <<<256, 256, 0, stream>>>(x, qw, kw, vw, vb, qa, ka, va);
  pam_attn <<<256, 256, 0, stream>>>(qa, ka, va, gam, y0, gs1, gs2);
  pam_stats<<<1, 64, 0, stream>>>(gs1, gs2, bnw, bnb, par);
  pam_apply<<<1024, 256, 0, stream>>>(y0, x, par, (float*)d_out);
}

// Round 5
// 266.071 us; speedup vs baseline: 1.0387x; 1.0387x over previous
//
#include <hip/hip_runtime.h>
#include <stdint.h>

using f16 = _Float16;

typedef _Float16 f16x8 __attribute__((ext_vector_type(8)));
typedef float f32x4 __attribute__((ext_vector_type(4)));

#define LOG2E 1.44269504088896340736f

__device__ __forceinline__ f16 f2h(float f) { return (f16)f; }  // RNE

#if __has_builtin(__builtin_amdgcn_exp2f)
__device__ __forceinline__ float fexp2(float x) { return __builtin_amdgcn_exp2f(x); }
#else
__device__ __forceinline__ float fexp2(float x) { return exp2f(x); }
#endif

__device__ __forceinline__ f16x8 cvt8(const float* p) {
  const float4 a = *(const float4*)p;
  const float4 b = *(const float4*)(p + 4);
  f16x8 r;
  r[0] = (f16)a.x; r[1] = (f16)a.y; r[2] = (f16)a.z; r[3] = (f16)a.w;
  r[4] = (f16)b.x; r[5] = (f16)b.y; r[6] = (f16)b.z; r[7] = (f16)b.w;
  return r;
}

// B=4, C=64, N=4096.  Global in/out tensors FP32; internal tensor-core path FP16.
// ws layout (bytes):
//   0        qa  f16 [4][4096][64]  (2 MB)   q * log2e, position-major
//   2 MB     ka  f16 [4][4096][64]  (2 MB)
//   4 MB     va  f16 [4][64][4096]  (2 MB)   channel-major
//   6 MB     y0  f32 [4][64][4096]  (4 MB)   gamma*attn_out, pre-BN
//   10 MB    stats: gs1[64] | gs2[64] | par float2[64]

// ---------------------------------------------------------------------------
// pre: conv1d q/k over channels, v = vw@x+vb via MFMA
// grid 256 = (b, n-tile of 64), 256 threads
// ---------------------------------------------------------------------------
__global__ __launch_bounds__(256, 1) void pam_pre(
    const float* __restrict__ x, const float* __restrict__ qw,
    const float* __restrict__ kw, const float* __restrict__ vw,
    const float* __restrict__ vb,
    f16* __restrict__ qa, f16* __restrict__ ka, f16* __restrict__ va)
{
  __shared__ alignas(16) f16 xt[64 * 72];   // xt[n][c] f16, row stride 72 elems
  const int tid = threadIdx.x;
  const int b = blockIdx.x >> 6;
  const int n0 = (blockIdx.x & 63) << 6;
  const int lane = tid & 63;
  const int wv = tid >> 6;
  const int quad = lane >> 4, l15 = lane & 15;

  // stage x[b][c][n0:+64] (fp32) transposed into xt[n][c] (f16)
  for (int p = 0; p < 4; ++p) {
    const int c = p * 16 + (tid >> 4);
    const int j0 = (tid & 15) << 2;
    const float4 v4 = *(const float4*)(x + ((size_t)(b * 64 + c) << 12) + n0 + j0);
    xt[(j0 + 0) * 72 + c] = f2h(v4.x);
    xt[(j0 + 1) * 72 + c] = f2h(v4.y);
    xt[(j0 + 2) * 72 + c] = f2h(v4.z);
    xt[(j0 + 3) * 72 + c] = f2h(v4.w);
  }
  __syncthreads();

  // conv along channel axis (SAME, zero pad), fp32 math on f16-rounded x
  const float qw0 = qw[0], qw1 = qw[1], qw2 = qw[2];
  const float kw0 = kw[0], kw1 = kw[1], kw2 = kw[2];
  for (int p = 0; p < 16; ++p) {
    const int c = lane;
    const int jr = (p << 2) + wv;
    const int n = n0 + jr;
    const float xm = (c > 0) ? (float)xt[jr * 72 + c - 1] : 0.f;
    const float x0 = (float)xt[jr * 72 + c];
    const float xp = (c < 63) ? (float)xt[jr * 72 + c + 1] : 0.f;
    const float qv = (qw0 * xm + qw1 * x0 + qw2 * xp) * LOG2E;  // log2-domain
    const float kv = kw0 * xm + kw1 * x0 + kw2 * xp;
    const size_t off = ((size_t)((b << 12) + n) << 6) + c;
    qa[off] = f2h(qv);
    ka[off] = f2h(kv);
  }

  // v[b][c][n] = vw @ x + vb via mfma 16x16x32 (wave wv -> c rows [16wv,+16))
  {
    const f16x8 a0 = cvt8(vw + (wv * 16 + l15) * 64 + quad * 8);
    const f16x8 a1 = cvt8(vw + (wv * 16 + l15) * 64 + quad * 8 + 32);
    f32x4 acc[4];
    for (int st = 0; st < 4; ++st) {
      const f16x8 b0 = *(const f16x8*)&xt[(st * 16 + l15) * 72 + quad * 8];
      const f16x8 b1 = *(const f16x8*)&xt[(st * 16 + l15) * 72 + quad * 8 + 32];
      f32x4 z = {0.f, 0.f, 0.f, 0.f};
      z = __builtin_amdgcn_mfma_f32_16x16x32_f16(a0, b0, z, 0, 0, 0);
      acc[st] = __builtin_amdgcn_mfma_f32_16x16x32_f16(a1, b1, z, 0, 0, 0);
    }
    const int cobase = wv * 16 + quad * 4;
    for (int st = 0; st < 4; ++st)
      for (int r = 0; r < 4; ++r) {
        const int co = cobase + r;
        const float val = acc[st][r] + vb[co];
        va[((size_t)(b * 64 + co) << 12) + n0 + st * 16 + l15] = f2h(val);
      }
  }
}

// ---------------------------------------------------------------------------
// attention: block = (b, 16 queries); 4 waves key-split (32 keys each, KT=128)
// pass 1: exact per-query row max (GEMM1 only).  pass 2: exact softmax + PV.
// grid 1024, 256 threads -> 4 blocks/CU, 16 waves/CU (occupancy fix vs r4).
// b = bx&3 -> batch spread across XCDs for K/V L2 residency.
// ---------------------------------------------------------------------------
__global__ __launch_bounds__(256, 4) void pam_attn(
    const f16* __restrict__ qa, const f16* __restrict__ ka,
    const f16* __restrict__ va, const float* __restrict__ gam,
    float* __restrict__ y0, float* __restrict__ gs1, float* __restrict__ gs2)
{
  __shared__ alignas(16) f16 pbuf[4][16 * 32];  // per-wave P [q][key], 64B rows, 16B-chunk xor swizzle
  __shared__ float ldsO[16 * 65];
  __shared__ float ldsL[4][16];
  __shared__ float ldsM[4][16];
  __shared__ float ldsInv[16];

  const int tid = threadIdx.x;
  const int wv = tid >> 6, lane = tid & 63;
  const int quad = lane >> 4, l15 = lane & 15;
  const int b = blockIdx.x & 3;
  const int qb0 = (blockIdx.x >> 2) << 4;

  for (int i = tid; i < 16 * 65; i += 256) ldsO[i] = 0.f;

  const int bn = b << 12;
  f16x8 bq[2];
  {
    const int q = qb0 + l15;
    const f16* qp = qa + ((size_t)(bn + q) << 6) + quad * 8;
    bq[0] = *(const f16x8*)qp;
    bq[1] = *(const f16x8*)(qp + 32);
  }

  // ---- pass 1: exact row max over this wave's 1024 keys, then merge ----
  float rmax = -3e38f;
  {
    f16x8 k0[2][2], k1[2][2];
    for (int mt = 0; mt < 2; ++mt) {
      const f16* kp = ka + ((size_t)(bn + wv * 32 + mt * 16 + l15) << 6) + quad * 8;
      k0[mt][0] = *(const f16x8*)kp;
      k0[mt][1] = *(const f16x8*)(kp + 32);
    }
#pragma unroll 2
    for (int kt = 0; kt < 32; ++kt) {
      const int kb2 = ((kt < 31) ? kt + 1 : 31) * 128 + wv * 32;
      for (int mt = 0; mt < 2; ++mt) {
        const f16* kp = ka + ((size_t)(bn + kb2 + mt * 16 + l15) << 6) + quad * 8;
        k1[mt][0] = *(const f16x8*)kp;
        k1[mt][1] = *(const f16x8*)(kp + 32);
      }
      for (int mt = 0; mt < 2; ++mt) {
        f32x4 z = {0.f, 0.f, 0.f, 0.f};
        z = __builtin_amdgcn_mfma_f32_16x16x32_f16(k0[mt][0], bq[0], z, 0, 0, 0);
        z = __builtin_amdgcn_mfma_f32_16x16x32_f16(k0[mt][1], bq[1], z, 0, 0, 0);
        rmax = fmaxf(rmax, fmaxf(fmaxf(z[0], z[1]), fmaxf(z[2], z[3])));
      }
      for (int mt = 0; mt < 2; ++mt) { k0[mt][0] = k1[mt][0]; k0[mt][1] = k1[mt][1]; }
    }
  }
  rmax = fmaxf(rmax, __shfl_xor(rmax, 16, 64));
  rmax = fmaxf(rmax, __shfl_xor(rmax, 32, 64));
  if (quad == 0) ldsM[wv][l15] = rmax;

  __syncthreads();  // ldsM published; ldsO zero-init done

  const float Mcol =
      fmaxf(fmaxf(ldsM[0][l15], ldsM[1][l15]), fmaxf(ldsM[2][l15], ldsM[3][l15]));

  f32x4 o[4] = {};
  float lpart = 0.f;
  f16* pb = pbuf[wv];

  // preload iteration 0 K/V fragments
  f16x8 ak[2][2], bv[4];
  {
    const int kb = wv * 32;
    for (int mt = 0; mt < 2; ++mt) {
      const f16* kp = ka + ((size_t)(bn + kb + mt * 16 + l15) << 6) + quad * 8;
      ak[mt][0] = *(const f16x8*)kp;
      ak[mt][1] = *(const f16x8*)(kp + 32);
    }
    for (int ct = 0; ct < 4; ++ct)
      bv[ct] = *(const f16x8*)(va + ((size_t)(b * 64 + ct * 16 + l15) << 12) + kb + quad * 8);
  }

#pragma unroll 2
  for (int kt = 0; kt < 32; ++kt) {
    // S^T = K_slice * Q^T, with C preloaded to -M (exact softmax shift)
    f32x4 s[2];
    for (int mt = 0; mt < 2; ++mt) {
      f32x4 z = {-Mcol, -Mcol, -Mcol, -Mcol};
      z = __builtin_amdgcn_mfma_f32_16x16x32_f16(ak[mt][0], bq[0], z, 0, 0, 0);
      s[mt] = __builtin_amdgcn_mfma_f32_16x16x32_f16(ak[mt][1], bq[1], z, 0, 0, 0);
    }

    // prefetch next iteration's K/V (overlaps softmax + GEMM2)
    f16x8 akn[2][2], bvn[4];
    {
      const int kb2 = ((kt < 31) ? kt + 1 : 31) * 128 + wv * 32;
      for (int mt = 0; mt < 2; ++mt) {
        const f16* kp = ka + ((size_t)(bn + kb2 + mt * 16 + l15) << 6) + quad * 8;
        akn[mt][0] = *(const f16x8*)kp;
        akn[mt][1] = *(const f16x8*)(kp + 32);
      }
      for (int ct = 0; ct < 4; ++ct)
        bvn[ct] = *(const f16x8*)(va + ((size_t)(b * 64 + ct * 16 + l15) << 12) + kb2 + quad * 8);
    }

    // P = exp2(S - M); accumulate l; pack 4 consecutive keys -> b64 LDS write
    {
      const int rowq = l15;
      char* rowp = (char*)pb + rowq * 64;
      const int sw = rowq & 3;
      for (int mt = 0; mt < 2; ++mt) {
        const float p0 = fexp2(s[mt][0]);
        const float p1 = fexp2(s[mt][1]);
        const float p2 = fexp2(s[mt][2]);
        const float p3 = fexp2(s[mt][3]);
        lpart += (p0 + p1) + (p2 + p3);
        union { f16 h[4]; uint2 u; } pk;
        pk.h[0] = f2h(p0); pk.h[1] = f2h(p1);
        pk.h[2] = f2h(p2); pk.h[3] = f2h(p3);
        const int cc = (2 * mt + (quad >> 1)) ^ sw;          // swizzled 16B-chunk pos
        *(uint2*)(rowp + cc * 16 + (quad & 1) * 8) = pk.u;
      }
    }
    __builtin_amdgcn_s_waitcnt(0xC07F);  // lgkmcnt(0): per-wave P writes visible

    // O[q][c] += P * V  (A = P from LDS, B = V channel-major, K = 32 keys)
    {
      const int rowq = l15;
      const f16x8 ap =
          *(const f16x8*)((const char*)pb + rowq * 64 + ((quad ^ (rowq & 3)) << 4));
      for (int ct = 0; ct < 4; ++ct)
        o[ct] = __builtin_amdgcn_mfma_f32_16x16x32_f16(ap, bv[ct], o[ct], 0, 0, 0);
    }

    for (int mt = 0; mt < 2; ++mt) { ak[mt][0] = akn[mt][0]; ak[mt][1] = akn[mt][1]; }
    for (int ct = 0; ct < 4; ++ct) bv[ct] = bvn[ct];
  }

  // l: reduce across quads (rows of S^T live across quads), publish per wave
  lpart += __shfl_xor(lpart, 16, 64);
  lpart += __shfl_xor(lpart, 32, 64);
  if (quad == 0) ldsL[wv][l15] = lpart;

  // merge partial O across the 4 key-split waves
  for (int ct = 0; ct < 4; ++ct) {
    const int col = ct * 16 + l15;
    for (int r = 0; r < 4; ++r)
      atomicAdd(&ldsO[(quad * 4 + r) * 65 + col], o[ct][r]);
  }
  __syncthreads();
  if (tid < 16)
    ldsInv[tid] = 1.f / (ldsL[0][tid] + ldsL[1][tid] + ldsL[2][tid] + ldsL[3][tid]);
  __syncthreads();

  // epilogue: y0[b][c][n] = gamma * O / l ; BN partial sums
  // thread -> (c = tid>>2, 4 consecutive q starting at (tid&3)*4)
  const float g = gam[0];
  {
    const int c = tid >> 2;
    const int q0 = (tid & 3) << 2;
    float4 v4;
    float* vp = &v4.x;
    float s1 = 0.f, s2 = 0.f;
    for (int r = 0; r < 4; ++r) {
      const float val = g * ldsO[(q0 + r) * 65 + c] * ldsInv[q0 + r];
      vp[r] = val;
      s1 += val;
      s2 += val * val;
    }
    *(float4*)(y0 + ((size_t)(b * 64 + c) << 12) + qb0 + q0) = v4;
    s1 += __shfl_xor(s1, 1, 64);
    s2 += __shfl_xor(s2, 1, 64);
    s1 += __shfl_xor(s1, 2, 64);
    s2 += __shfl_xor(s2, 2, 64);
    if ((tid & 3) == 0) {
      atomicAdd(&gs1[c], s1);
      atomicAdd(&gs2[c], s2);
    }
  }
}

// ---------------------------------------------------------------------------
__global__ __launch_bounds__(64, 1) void pam_stats(
    const float* __restrict__ gs1, const float* __restrict__ gs2,
    const float* __restrict__ bnw, const float* __restrict__ bnb,
    float2* __restrict__ par)
{
  const int c = threadIdx.x;
  const float inv_n = 1.f / 16384.f;
  const float mean = gs1[c] * inv_n;
  const float var = fmaxf(gs2[c] * inv_n - mean * mean, 0.f);
  const float sc = bnw[c] * rsqrtf(var + 1e-5f);
  par[c] = make_float2(sc, bnb[c] - mean * sc);
}

// ---------------------------------------------------------------------------
__global__ __launch_bounds__(256, 1) void pam_apply(
    const float* __restrict__ y0, const float* __restrict__ x,
    const float2* __restrict__ par, float* __restrict__ out)
{
  const int i = (blockIdx.x * 256 + threadIdx.x) << 2;   // 4 elems/thread, exact cover
  const int c = (i >> 12) & 63;
  const float2 p = par[c];
  const float4 y = *(const float4*)(y0 + i);
  const float4 xv = *(const float4*)(x + i);
  float4 r;
  r.x = y.x * p.x + p.y + xv.x;
  r.y = y.y * p.x + p.y + xv.y;
  r.z = y.z * p.x + p.y + xv.z;
  r.w = y.w * p.x + p.y + xv.w;
  *(float4*)(out + i) = r;
}

// ---------------------------------------------------------------------------
extern "C" void kernel_launch(void* const* d_in, const int* in_sizes, int n_in,
                              void* d_out, int out_size, void* d_ws, size_t ws_size,
                              hipStream_t stream)
{
  (void)in_sizes; (void)n_in; (void)out_size; (void)ws_size;
  const float* x   = (const float*)d_in[0];
  const float* qw  = (const float*)d_in[1];
  const float* kw  = (const float*)d_in[2];
  const float* vw  = (const float*)d_in[3];
  const float* vb  = (const float*)d_in[4];
  const float* gam = (const float*)d_in[5];
  const float* bnw = (const float*)d_in[6];
  const float* bnb = (const float*)d_in[7];

  char* ws = (char*)d_ws;
  f16*   qa  = (f16*)(ws);
  f16*   ka  = (f16*)(ws + (2u << 20));
  f16*   va  = (f16*)(ws + (4u << 20));
  float* y0  = (float*)(ws + (6u << 20));
  char*  st  = ws + (10u << 20);
  float*  gs1  = (float*)(st);           // 64 floats
  float*  gs2  = (float*)(st + 256);     // 64 floats
  float2* par  = (float2*)(st + 512);    // 64 float2

  hipMemsetAsync(st, 0, 512, stream);
  pam_pre  <<<256, 256, 0, stream>>>(x, qw, kw, vw, vb, qa, ka, va);
  pam_attn <<<1024, 256, 0, stream>>>(qa, ka, va, gam, y0, gs1, gs2);
  pam_stats<<<1, 64, 0, stream>>>(gs1, gs2, bnw, bnb, par);
  pam_apply<<<1024, 256, 0, stream>>>(y0, x, par, (float*)d_out);
}

// Round 6
// 264.166 us; speedup vs baseline: 1.0462x; 1.0072x over previous
//
#include <hip/hip_runtime.h>
#include <stdint.h>

using f16 = _Float16;

typedef _Float16 f16x8 __attribute__((ext_vector_type(8)));
typedef float f32x4 __attribute__((ext_vector_type(4)));

#define LOG2E 1.44269504088896340736f

__device__ __forceinline__ f16 f2h(float f) { return (f16)f; }  // RNE

#if __has_builtin(__builtin_amdgcn_exp2f)
__device__ __forceinline__ float fexp2(float x) { return __builtin_amdgcn_exp2f(x); }
#else
__device__ __forceinline__ float fexp2(float x) { return exp2f(x); }
#endif

__device__ __forceinline__ f16x8 cvt8(const float* p) {
  const float4 a = *(const float4*)p;
  const float4 b = *(const float4*)(p + 4);
  f16x8 r;
  r[0] = (f16)a.x; r[1] = (f16)a.y; r[2] = (f16)a.z; r[3] = (f16)a.w;
  r[4] = (f16)b.x; r[5] = (f16)b.y; r[6] = (f16)b.z; r[7] = (f16)b.w;
  return r;
}

// B=4, C=64, N=4096.  Global in/out tensors FP32; internal tensor-core path FP16.
// ws layout (bytes):
//   0        qa  f16 [4][4096][64]  (2 MB)   q * log2e, position-major
//   2 MB     ka  f16 [4][4096][64]  (2 MB)
//   4 MB     va  f16 [4][64][4096]  (2 MB)   channel-major
//   6 MB     y0  f32 [4][64][4096]  (4 MB)   gamma*attn_out, pre-BN
//   10 MB    stats: gs1[64] | gs2[64] | par float2[64]

// ---------------------------------------------------------------------------
// pre: conv1d q/k over channels, v = vw@x+vb via MFMA
// grid 256 = (b, n-tile of 64), 256 threads
// ---------------------------------------------------------------------------
__global__ __launch_bounds__(256, 1) void pam_pre(
    const float* __restrict__ x, const float* __restrict__ qw,
    const float* __restrict__ kw, const float* __restrict__ vw,
    const float* __restrict__ vb,
    f16* __restrict__ qa, f16* __restrict__ ka, f16* __restrict__ va)
{
  __shared__ alignas(16) f16 xt[64 * 72];   // xt[n][c] f16, row stride 72 elems
  const int tid = threadIdx.x;
  const int b = blockIdx.x >> 6;
  const int n0 = (blockIdx.x & 63) << 6;
  const int lane = tid & 63;
  const int wv = tid >> 6;
  const int quad = lane >> 4, l15 = lane & 15;

  // stage x[b][c][n0:+64] (fp32) transposed into xt[n][c] (f16)
  for (int p = 0; p < 4; ++p) {
    const int c = p * 16 + (tid >> 4);
    const int j0 = (tid & 15) << 2;
    const float4 v4 = *(const float4*)(x + ((size_t)(b * 64 + c) << 12) + n0 + j0);
    xt[(j0 + 0) * 72 + c] = f2h(v4.x);
    xt[(j0 + 1) * 72 + c] = f2h(v4.y);
    xt[(j0 + 2) * 72 + c] = f2h(v4.z);
    xt[(j0 + 3) * 72 + c] = f2h(v4.w);
  }
  __syncthreads();

  // conv along channel axis (SAME, zero pad), fp32 math on f16-rounded x
  const float qw0 = qw[0], qw1 = qw[1], qw2 = qw[2];
  const float kw0 = kw[0], kw1 = kw[1], kw2 = kw[2];
  for (int p = 0; p < 16; ++p) {
    const int c = lane;
    const int jr = (p << 2) + wv;
    const int n = n0 + jr;
    const float xm = (c > 0) ? (float)xt[jr * 72 + c - 1] : 0.f;
    const float x0 = (float)xt[jr * 72 + c];
    const float xp = (c < 63) ? (float)xt[jr * 72 + c + 1] : 0.f;
    const float qv = (qw0 * xm + qw1 * x0 + qw2 * xp) * LOG2E;  // log2-domain
    const float kv = kw0 * xm + kw1 * x0 + kw2 * xp;
    const size_t off = ((size_t)((b << 12) + n) << 6) + c;
    qa[off] = f2h(qv);
    ka[off] = f2h(kv);
  }

  // v[b][c][n] = vw @ x + vb via mfma 16x16x32 (wave wv -> c rows [16wv,+16))
  {
    const f16x8 a0 = cvt8(vw + (wv * 16 + l15) * 64 + quad * 8);
    const f16x8 a1 = cvt8(vw + (wv * 16 + l15) * 64 + quad * 8 + 32);
    f32x4 acc[4];
    for (int st = 0; st < 4; ++st) {
      const f16x8 b0 = *(const f16x8*)&xt[(st * 16 + l15) * 72 + quad * 8];
      const f16x8 b1 = *(const f16x8*)&xt[(st * 16 + l15) * 72 + quad * 8 + 32];
      f32x4 z = {0.f, 0.f, 0.f, 0.f};
      z = __builtin_amdgcn_mfma_f32_16x16x32_f16(a0, b0, z, 0, 0, 0);
      acc[st] = __builtin_amdgcn_mfma_f32_16x16x32_f16(a1, b1, z, 0, 0, 0);
    }
    const int cobase = wv * 16 + quad * 4;
    for (int st = 0; st < 4; ++st)
      for (int r = 0; r < 4; ++r) {
        const int co = cobase + r;
        const float val = acc[st][r] + vb[co];
        va[((size_t)(b * 64 + co) << 12) + n0 + st * 16 + l15] = f2h(val);
      }
  }
}

// ---------------------------------------------------------------------------
// attention: block = (b, 16 queries); 4 waves key-split (32 keys each, KT=128)
// pass 1: exact per-query row max (GEMM1 only).  pass 2: exact softmax + PV.
// grid 1024, 256 threads -> 4 blocks/CU, 16 waves/CU.
// NO manual prefetch double-buffer: r5 post-mortem showed it forced scratch
// spills (VGPR 64!) putting a global round-trip on the per-iter critical path.
// Live state now ~90 regs -> fits 128-cap of (256,4) with no spill; latency
// hidden by 4 waves/SIMD TLP + compiler-scheduled vmcnt.
// ---------------------------------------------------------------------------
__global__ __launch_bounds__(256, 4) void pam_attn(
    const f16* __restrict__ qa, const f16* __restrict__ ka,
    const f16* __restrict__ va, const float* __restrict__ gam,
    float* __restrict__ y0, float* __restrict__ gs1, float* __restrict__ gs2)
{
  __shared__ alignas(16) f16 pbuf[4][16 * 32];  // per-wave P [q][key], 64B rows, 16B-chunk xor swizzle
  __shared__ float ldsO[16 * 65];
  __shared__ float ldsL[4][16];
  __shared__ float ldsM[4][16];
  __shared__ float ldsInv[16];

  const int tid = threadIdx.x;
  const int wv = tid >> 6, lane = tid & 63;
  const int quad = lane >> 4, l15 = lane & 15;
  const int b = blockIdx.x & 3;
  const int qb0 = (blockIdx.x >> 2) << 4;

  for (int i = tid; i < 16 * 65; i += 256) ldsO[i] = 0.f;

  const int bn = b << 12;
  f16x8 bq[2];
  {
    const int q = qb0 + l15;
    const f16* qp = qa + ((size_t)(bn + q) << 6) + quad * 8;
    bq[0] = *(const f16x8*)qp;
    bq[1] = *(const f16x8*)(qp + 32);
  }

  // ---- pass 1: exact row max over this wave's 1024 keys, then merge ----
  float rmax = -3e38f;
#pragma unroll 1
  for (int kt = 0; kt < 32; ++kt) {
    const int kb = kt * 128 + wv * 32;
    for (int mt = 0; mt < 2; ++mt) {
      const f16* kp = ka + ((size_t)(bn + kb + mt * 16 + l15) << 6) + quad * 8;
      const f16x8 k0 = *(const f16x8*)kp;
      const f16x8 k1 = *(const f16x8*)(kp + 32);
      f32x4 z = {0.f, 0.f, 0.f, 0.f};
      z = __builtin_amdgcn_mfma_f32_16x16x32_f16(k0, bq[0], z, 0, 0, 0);
      z = __builtin_amdgcn_mfma_f32_16x16x32_f16(k1, bq[1], z, 0, 0, 0);
      rmax = fmaxf(rmax, fmaxf(fmaxf(z[0], z[1]), fmaxf(z[2], z[3])));
    }
  }
  rmax = fmaxf(rmax, __shfl_xor(rmax, 16, 64));
  rmax = fmaxf(rmax, __shfl_xor(rmax, 32, 64));
  if (quad == 0) ldsM[wv][l15] = rmax;

  __syncthreads();  // ldsM published; ldsO zero-init done

  const float Mcol =
      fmaxf(fmaxf(ldsM[0][l15], ldsM[1][l15]), fmaxf(ldsM[2][l15], ldsM[3][l15]));

  f32x4 o[4] = {};
  float lpart = 0.f;
  f16* pb = pbuf[wv];

#pragma unroll 1
  for (int kt = 0; kt < 32; ++kt) {
    const int kb = kt * 128 + wv * 32;

    // load this iteration's K and V fragments (compiler schedules vmcnt)
    f16x8 ak[2][2], bv[4];
    for (int mt = 0; mt < 2; ++mt) {
      const f16* kp = ka + ((size_t)(bn + kb + mt * 16 + l15) << 6) + quad * 8;
      ak[mt][0] = *(const f16x8*)kp;
      ak[mt][1] = *(const f16x8*)(kp + 32);
    }
    for (int ct = 0; ct < 4; ++ct)
      bv[ct] = *(const f16x8*)(va + ((size_t)(b * 64 + ct * 16 + l15) << 12) + kb + quad * 8);

    // S^T = K_slice * Q^T, with C preloaded to -M (exact softmax shift)
    f32x4 s[2];
    for (int mt = 0; mt < 2; ++mt) {
      f32x4 z = {-Mcol, -Mcol, -Mcol, -Mcol};
      z = __builtin_amdgcn_mfma_f32_16x16x32_f16(ak[mt][0], bq[0], z, 0, 0, 0);
      s[mt] = __builtin_amdgcn_mfma_f32_16x16x32_f16(ak[mt][1], bq[1], z, 0, 0, 0);
    }

    // P = exp2(S - M); accumulate l; pack 4 consecutive keys -> b64 LDS write
    {
      const int rowq = l15;
      char* rowp = (char*)pb + rowq * 64;
      const int sw = rowq & 3;
      for (int mt = 0; mt < 2; ++mt) {
        const float p0 = fexp2(s[mt][0]);
        const float p1 = fexp2(s[mt][1]);
        const float p2 = fexp2(s[mt][2]);
        const float p3 = fexp2(s[mt][3]);
        lpart += (p0 + p1) + (p2 + p3);
        union { f16 h[4]; uint2 u; } pk;
        pk.h[0] = f2h(p0); pk.h[1] = f2h(p1);
        pk.h[2] = f2h(p2); pk.h[3] = f2h(p3);
        const int cc = (2 * mt + (quad >> 1)) ^ sw;          // swizzled 16B-chunk pos
        *(uint2*)(rowp + cc * 16 + (quad & 1) * 8) = pk.u;
      }
    }
    __builtin_amdgcn_s_waitcnt(0xC07F);  // lgkmcnt(0): per-wave P writes visible

    // O[q][c] += P * V  (A = P from LDS, B = V channel-major, K = 32 keys)
    {
      const int rowq = l15;
      const f16x8 ap =
          *(const f16x8*)((const char*)pb + rowq * 64 + ((quad ^ (rowq & 3)) << 4));
      for (int ct = 0; ct < 4; ++ct)
        o[ct] = __builtin_amdgcn_mfma_f32_16x16x32_f16(ap, bv[ct], o[ct], 0, 0, 0);
    }
  }

  // l: reduce across quads (rows of S^T live across quads), publish per wave
  lpart += __shfl_xor(lpart, 16, 64);
  lpart += __shfl_xor(lpart, 32, 64);
  if (quad == 0) ldsL[wv][l15] = lpart;

  // merge partial O across the 4 key-split waves
  for (int ct = 0; ct < 4; ++ct) {
    const int col = ct * 16 + l15;
    for (int r = 0; r < 4; ++r)
      atomicAdd(&ldsO[(quad * 4 + r) * 65 + col], o[ct][r]);
  }
  __syncthreads();
  if (tid < 16)
    ldsInv[tid] = 1.f / (ldsL[0][tid] + ldsL[1][tid] + ldsL[2][tid] + ldsL[3][tid]);
  __syncthreads();

  // epilogue: y0[b][c][n] = gamma * O / l ; BN partial sums
  // thread -> (c = tid>>2, 4 consecutive q starting at (tid&3)*4)
  const float g = gam[0];
  {
    const int c = tid >> 2;
    const int q0 = (tid & 3) << 2;
    float4 v4;
    float* vp = &v4.x;
    float s1 = 0.f, s2 = 0.f;
    for (int r = 0; r < 4; ++r) {
      const float val = g * ldsO[(q0 + r) * 65 + c] * ldsInv[q0 + r];
      vp[r] = val;
      s1 += val;
      s2 += val * val;
    }
    *(float4*)(y0 + ((size_t)(b * 64 + c) << 12) + qb0 + q0) = v4;
    s1 += __shfl_xor(s1, 1, 64);
    s2 += __shfl_xor(s2, 1, 64);
    s1 += __shfl_xor(s1, 2, 64);
    s2 += __shfl_xor(s2, 2, 64);
    if ((tid & 3) == 0) {
      atomicAdd(&gs1[c], s1);
      atomicAdd(&gs2[c], s2);
    }
  }
}

// ---------------------------------------------------------------------------
__global__ __launch_bounds__(64, 1) void pam_stats(
    const float* __restrict__ gs1, const float* __restrict__ gs2,
    const float* __restrict__ bnw, const float* __restrict__ bnb,
    float2* __restrict__ par)
{
  const int c = threadIdx.x;
  const float inv_n = 1.f / 16384.f;
  const float mean = gs1[c] * inv_n;
  const float var = fmaxf(gs2[c] * inv_n - mean * mean, 0.f);
  const float sc = bnw[c] * rsqrtf(var + 1e-5f);
  par[c] = make_float2(sc, bnb[c] - mean * sc);
}

// ---------------------------------------------------------------------------
__global__ __launch_bounds__(256, 1) void pam_apply(
    const float* __restrict__ y0, const float* __restrict__ x,
    const float2* __restrict__ par, float* __restrict__ out)
{
  const int i = (blockIdx.x * 256 + threadIdx.x) << 2;   // 4 elems/thread, exact cover
  const int c = (i >> 12) & 63;
  const float2 p = par[c];
  const float4 y = *(const float4*)(y0 + i);
  const float4 xv = *(const float4*)(x + i);
  float4 r;
  r.x = y.x * p.x + p.y + xv.x;
  r.y = y.y * p.x + p.y + xv.y;
  r.z = y.z * p.x + p.y + xv.z;
  r.w = y.w * p.x + p.y + xv.w;
  *(float4*)(out + i) = r;
}

// ---------------------------------------------------------------------------
extern "C" void kernel_launch(void* const* d_in, const int* in_sizes, int n_in,
                              void* d_out, int out_size, void* d_ws, size_t ws_size,
                              hipStream_t stream)
{
  (void)in_sizes; (void)n_in; (void)out_size; (void)ws_size;
  const float* x   = (const float*)d_in[0];
  const float* qw  = (const float*)d_in[1];
  const float* kw  = (const float*)d_in[2];
  const float* vw  = (const float*)d_in[3];
  const float* vb  = (const float*)d_in[4];
  const float* gam = (const float*)d_in[5];
  const float* bnw = (const float*)d_in[6];
  const float* bnb = (const float*)d_in[7];

  char* ws = (char*)d_ws;
  f16*   qa  = (f16*)(ws);
  f16*   ka  = (f16*)(ws + (2u << 20));
  f16*   va  = (f16*)(ws + (4u << 20));
  float* y0  = (float*)(ws + (6u << 20));
  char*  st  = ws + (10u << 20);
  float*  gs1  = (float*)(st);           // 64 floats
  float*  gs2  = (float*)(st + 256);     // 64 floats
  float2* par  = (float2*)(st + 512);    // 64 float2

  hipMemsetAsync(st, 0, 512, stream);
  pam_pre  <<<256, 256, 0, stream>>>(x, qw, kw, vw, vb, qa, ka, va);
  pam_attn <<<1024, 256, 0, stream>>>(qa, ka, va, gam, y0, gs1, gs2);
  pam_stats<<<1, 64, 0, stream>>>(gs1, gs2, bnw, bnb, par);
  pam_apply<<<1024, 256, 0, stream>>>(y0, x, par, (float*)d_out);
}

// Round 7
// 195.640 us; speedup vs baseline: 1.4126x; 1.3503x over previous
//
#include <hip/hip_runtime.h>
#include <stdint.h>

using f16 = _Float16;

typedef _Float16 f16x8 __attribute__((ext_vector_type(8)));
typedef float f32x4 __attribute__((ext_vector_type(4)));

#define LOG2E 1.44269504088896340736f

__device__ __forceinline__ f16 f2h(float f) { return (f16)f; }  // RNE

#if __has_builtin(__builtin_amdgcn_exp2f)
__device__ __forceinline__ float fexp2(float x) { return __builtin_amdgcn_exp2f(x); }
#else
__device__ __forceinline__ float fexp2(float x) { return exp2f(x); }
#endif

__device__ __forceinline__ f16x8 cvt8(const float* p) {
  const float4 a = *(const float4*)p;
  const float4 b = *(const float4*)(p + 4);
  f16x8 r;
  r[0] = (f16)a.x; r[1] = (f16)a.y; r[2] = (f16)a.z; r[3] = (f16)a.w;
  r[4] = (f16)b.x; r[5] = (f16)b.y; r[6] = (f16)b.z; r[7] = (f16)b.w;
  return r;
}

// B=4, C=64, N=4096.  Global in/out tensors FP32; internal tensor-core path FP16.
// ws layout (bytes):
//   0        qa  f16 [4][4096][64]  (2 MB)   q * log2e, position-major
//   2 MB     ka  f16 [4][4096][64]  (2 MB)
//   4 MB     va  f16 [4][64][4096]  (2 MB)   channel-major
//   6 MB     y0  f32 [4][64][4096]  (4 MB)   gamma*attn_out, pre-BN
//   10 MB    stats: gs1[64] | gs2[64] | par float2[64]

// ---------------------------------------------------------------------------
// pre: conv1d q/k over channels, v = vw@x+vb via MFMA
// grid 256 = (b, n-tile of 64), 256 threads
// ---------------------------------------------------------------------------
__global__ __launch_bounds__(256, 1) void pam_pre(
    const float* __restrict__ x, const float* __restrict__ qw,
    const float* __restrict__ kw, const float* __restrict__ vw,
    const float* __restrict__ vb,
    f16* __restrict__ qa, f16* __restrict__ ka, f16* __restrict__ va)
{
  __shared__ alignas(16) f16 xt[64 * 72];   // xt[n][c] f16, row stride 72 elems
  const int tid = threadIdx.x;
  const int b = blockIdx.x >> 6;
  const int n0 = (blockIdx.x & 63) << 6;
  const int lane = tid & 63;
  const int wv = tid >> 6;
  const int quad = lane >> 4, l15 = lane & 15;

  // stage x[b][c][n0:+64] (fp32) transposed into xt[n][c] (f16)
  for (int p = 0; p < 4; ++p) {
    const int c = p * 16 + (tid >> 4);
    const int j0 = (tid & 15) << 2;
    const float4 v4 = *(const float4*)(x + ((size_t)(b * 64 + c) << 12) + n0 + j0);
    xt[(j0 + 0) * 72 + c] = f2h(v4.x);
    xt[(j0 + 1) * 72 + c] = f2h(v4.y);
    xt[(j0 + 2) * 72 + c] = f2h(v4.z);
    xt[(j0 + 3) * 72 + c] = f2h(v4.w);
  }
  __syncthreads();

  // conv along channel axis (SAME, zero pad), fp32 math on f16-rounded x
  const float qw0 = qw[0], qw1 = qw[1], qw2 = qw[2];
  const float kw0 = kw[0], kw1 = kw[1], kw2 = kw[2];
  for (int p = 0; p < 16; ++p) {
    const int c = lane;
    const int jr = (p << 2) + wv;
    const int n = n0 + jr;
    const float xm = (c > 0) ? (float)xt[jr * 72 + c - 1] : 0.f;
    const float x0 = (float)xt[jr * 72 + c];
    const float xp = (c < 63) ? (float)xt[jr * 72 + c + 1] : 0.f;
    const float qv = (qw0 * xm + qw1 * x0 + qw2 * xp) * LOG2E;  // log2-domain
    const float kv = kw0 * xm + kw1 * x0 + kw2 * xp;
    const size_t off = ((size_t)((b << 12) + n) << 6) + c;
    qa[off] = f2h(qv);
    ka[off] = f2h(kv);
  }

  // v[b][c][n] = vw @ x + vb via mfma 16x16x32 (wave wv -> c rows [16wv,+16))
  {
    const f16x8 a0 = cvt8(vw + (wv * 16 + l15) * 64 + quad * 8);
    const f16x8 a1 = cvt8(vw + (wv * 16 + l15) * 64 + quad * 8 + 32);
    f32x4 acc[4];
    for (int st = 0; st < 4; ++st) {
      const f16x8 b0 = *(const f16x8*)&xt[(st * 16 + l15) * 72 + quad * 8];
      const f16x8 b1 = *(const f16x8*)&xt[(st * 16 + l15) * 72 + quad * 8 + 32];
      f32x4 z = {0.f, 0.f, 0.f, 0.f};
      z = __builtin_amdgcn_mfma_f32_16x16x32_f16(a0, b0, z, 0, 0, 0);
      acc[st] = __builtin_amdgcn_mfma_f32_16x16x32_f16(a1, b1, z, 0, 0, 0);
    }
    const int cobase = wv * 16 + quad * 4;
    for (int st = 0; st < 4; ++st)
      for (int r = 0; r < 4; ++r) {
        const int co = cobase + r;
        const float val = acc[st][r] + vb[co];
        va[((size_t)(b * 64 + co) << 12) + n0 + st * 16 + l15] = f2h(val);
      }
  }
}

// ---------------------------------------------------------------------------
// attention: block = (b, 32 queries = 2 q-tiles); 4 waves key-split (32 keys
// each, KT=128). pass 1: exact per-query row max; pass 2: exact softmax + PV.
// grid 512, 256 threads -> 2 blocks/CU, 8 waves/CU.
// K fragments reused across both q-tiles (halves per-query K traffic vs r6).
// Per-block PHASE ROTATION of the K-loop decorrelates the L2 access streams
// of blocks sharing a batch (anti-convoy); max/sum are order-invariant so the
// result is bit-identical.
// ---------------------------------------------------------------------------
__global__ __launch_bounds__(256, 2) void pam_attn(
    const f16* __restrict__ qa, const f16* __restrict__ ka,
    const f16* __restrict__ va, const float* __restrict__ gam,
    float* __restrict__ y0, float* __restrict__ gs1, float* __restrict__ gs2)
{
  __shared__ alignas(16) f16 pbuf[4][32 * 32];  // per-wave P [q][key], 64B rows, 16B-chunk xor swizzle
  __shared__ float ldsO[32 * 65];
  __shared__ float ldsL[4][32];
  __shared__ float ldsM[4][32];
  __shared__ float ldsInv[32];

  const int tid = threadIdx.x;
  const int wv = tid >> 6, lane = tid & 63;
  const int quad = lane >> 4, l15 = lane & 15;
  const int b = blockIdx.x & 3;
  const int qt_idx = blockIdx.x >> 2;          // 0..127
  const int qb0 = qt_idx << 5;
  const int phase = qt_idx & 31;               // anti-convoy rotation

  for (int i = tid; i < 32 * 65; i += 256) ldsO[i] = 0.f;

  const int bn = b << 12;
  f16x8 bq[2][2];
  for (int qt = 0; qt < 2; ++qt) {
    const int q = qb0 + qt * 16 + l15;
    const f16* qp = qa + ((size_t)(bn + q) << 6) + quad * 8;
    bq[qt][0] = *(const f16x8*)qp;
    bq[qt][1] = *(const f16x8*)(qp + 32);
  }

  // ---- pass 1: exact row max over this wave's 1024 keys, then merge ----
  float rmax[2] = {-3e38f, -3e38f};
#pragma unroll 1
  for (int kt = 0; kt < 32; ++kt) {
    const int kb = (((kt + phase) & 31) << 7) + wv * 32;
    for (int mt = 0; mt < 2; ++mt) {
      const f16* kp = ka + ((size_t)(bn + kb + mt * 16 + l15) << 6) + quad * 8;
      const f16x8 k0 = *(const f16x8*)kp;
      const f16x8 k1 = *(const f16x8*)(kp + 32);
      for (int qt = 0; qt < 2; ++qt) {
        f32x4 z = {0.f, 0.f, 0.f, 0.f};
        z = __builtin_amdgcn_mfma_f32_16x16x32_f16(k0, bq[qt][0], z, 0, 0, 0);
        z = __builtin_amdgcn_mfma_f32_16x16x32_f16(k1, bq[qt][1], z, 0, 0, 0);
        rmax[qt] = fmaxf(rmax[qt], fmaxf(fmaxf(z[0], z[1]), fmaxf(z[2], z[3])));
      }
    }
  }
  for (int qt = 0; qt < 2; ++qt) {
    float v = rmax[qt];
    v = fmaxf(v, __shfl_xor(v, 16, 64));
    v = fmaxf(v, __shfl_xor(v, 32, 64));
    if (quad == 0) ldsM[wv][qt * 16 + l15] = v;
  }

  __syncthreads();  // ldsM published; ldsO zero-init done

  float Mcol[2];
  for (int qt = 0; qt < 2; ++qt) {
    const int q = qt * 16 + l15;
    Mcol[qt] = fmaxf(fmaxf(ldsM[0][q], ldsM[1][q]), fmaxf(ldsM[2][q], ldsM[3][q]));
  }

  f32x4 o[2][4] = {};
  float lpart[2] = {0.f, 0.f};
  f16* pb = pbuf[wv];

#pragma unroll 1
  for (int kt = 0; kt < 32; ++kt) {
    const int kb = (((kt + phase) & 31) << 7) + wv * 32;

    // load this iteration's K and V fragments (compiler schedules vmcnt)
    f16x8 ak[2][2], bv[4];
    for (int mt = 0; mt < 2; ++mt) {
      const f16* kp = ka + ((size_t)(bn + kb + mt * 16 + l15) << 6) + quad * 8;
      ak[mt][0] = *(const f16x8*)kp;
      ak[mt][1] = *(const f16x8*)(kp + 32);
    }
    for (int ct = 0; ct < 4; ++ct)
      bv[ct] = *(const f16x8*)(va + ((size_t)(b * 64 + ct * 16 + l15) << 12) + kb + quad * 8);

    // S^T = K_slice * Q^T, with C preloaded to -M (exact softmax shift)
    // P = exp2(S - M); accumulate l; pack 4 consecutive keys -> b64 LDS write
    for (int qt = 0; qt < 2; ++qt) {
      const int rowq = qt * 16 + l15;
      char* rowp = (char*)pb + rowq * 64;
      const int sw = rowq & 3;
      for (int mt = 0; mt < 2; ++mt) {
        f32x4 z = {-Mcol[qt], -Mcol[qt], -Mcol[qt], -Mcol[qt]};
        z = __builtin_amdgcn_mfma_f32_16x16x32_f16(ak[mt][0], bq[qt][0], z, 0, 0, 0);
        z = __builtin_amdgcn_mfma_f32_16x16x32_f16(ak[mt][1], bq[qt][1], z, 0, 0, 0);
        const float p0 = fexp2(z[0]);
        const float p1 = fexp2(z[1]);
        const float p2 = fexp2(z[2]);
        const float p3 = fexp2(z[3]);
        lpart[qt] += (p0 + p1) + (p2 + p3);
        union { f16 h[4]; uint2 u; } pk;
        pk.h[0] = f2h(p0); pk.h[1] = f2h(p1);
        pk.h[2] = f2h(p2); pk.h[3] = f2h(p3);
        const int cc = (2 * mt + (quad >> 1)) ^ sw;          // swizzled 16B-chunk pos
        *(uint2*)(rowp + cc * 16 + (quad & 1) * 8) = pk.u;
      }
    }
    __builtin_amdgcn_s_waitcnt(0xC07F);  // lgkmcnt(0): per-wave P writes visible

    // O[q][c] += P * V  (A = P from LDS, B = V channel-major, K = 32 keys)
    for (int qt = 0; qt < 2; ++qt) {
      const int rowq = qt * 16 + l15;
      const f16x8 ap =
          *(const f16x8*)((const char*)pb + rowq * 64 + ((quad ^ (rowq & 3)) << 4));
      for (int ct = 0; ct < 4; ++ct)
        o[qt][ct] = __builtin_amdgcn_mfma_f32_16x16x32_f16(ap, bv[ct], o[qt][ct], 0, 0, 0);
    }
  }

  // l: reduce across quads (rows of S^T live across quads), publish per wave
  for (int qt = 0; qt < 2; ++qt) {
    float v = lpart[qt];
    v += __shfl_xor(v, 16, 64);
    v += __shfl_xor(v, 32, 64);
    if (quad == 0) ldsL[wv][qt * 16 + l15] = v;
  }

  // merge partial O across the 4 key-split waves
  for (int qt = 0; qt < 2; ++qt) {
    const int row = qt * 16 + quad * 4;
    for (int ct = 0; ct < 4; ++ct) {
      const int col = ct * 16 + l15;
      for (int r = 0; r < 4; ++r)
        atomicAdd(&ldsO[(row + r) * 65 + col], o[qt][ct][r]);
    }
  }
  __syncthreads();
  if (tid < 32)
    ldsInv[tid] = 1.f / (ldsL[0][tid] + ldsL[1][tid] + ldsL[2][tid] + ldsL[3][tid]);
  __syncthreads();

  // epilogue: y0[b][c][n] = gamma * O / l ; BN partial sums
  // thread -> (c = tid>>2, 8 consecutive q starting at (tid&3)*8)
  const float g = gam[0];
  {
    const int c = tid >> 2;
    const int q0 = (tid & 3) << 3;
    float s1 = 0.f, s2 = 0.f;
    float4 v4a, v4b;
    float* va4 = &v4a.x;
    float* vb4 = &v4b.x;
    for (int r = 0; r < 4; ++r) {
      const float val = g * ldsO[(q0 + r) * 65 + c] * ldsInv[q0 + r];
      va4[r] = val; s1 += val; s2 += val * val;
    }
    for (int r = 0; r < 4; ++r) {
      const float val = g * ldsO[(q0 + 4 + r) * 65 + c] * ldsInv[q0 + 4 + r];
      vb4[r] = val; s1 += val; s2 += val * val;
    }
    float* dst = y0 + ((size_t)(b * 64 + c) << 12) + qb0 + q0;
    *(float4*)dst = v4a;
    *(float4*)(dst + 4) = v4b;
    s1 += __shfl_xor(s1, 1, 64);
    s2 += __shfl_xor(s2, 1, 64);
    s1 += __shfl_xor(s1, 2, 64);
    s2 += __shfl_xor(s2, 2, 64);
    if ((tid & 3) == 0) {
      atomicAdd(&gs1[c], s1);
      atomicAdd(&gs2[c], s2);
    }
  }
}

// ---------------------------------------------------------------------------
__global__ __launch_bounds__(64, 1) void pam_stats(
    const float* __restrict__ gs1, const float* __restrict__ gs2,
    const float* __restrict__ bnw, const float* __restrict__ bnb,
    float2* __restrict__ par)
{
  const int c = threadIdx.x;
  const float inv_n = 1.f / 16384.f;
  const float mean = gs1[c] * inv_n;
  const float var = fmaxf(gs2[c] * inv_n - mean * mean, 0.f);
  const float sc = bnw[c] * rsqrtf(var + 1e-5f);
  par[c] = make_float2(sc, bnb[c] - mean * sc);
}

// ---------------------------------------------------------------------------
__global__ __launch_bounds__(256, 1) void pam_apply(
    const float* __restrict__ y0, const float* __restrict__ x,
    const float2* __restrict__ par, float* __restrict__ out)
{
  const int i = (blockIdx.x * 256 + threadIdx.x) << 2;   // 4 elems/thread, exact cover
  const int c = (i >> 12) & 63;
  const float2 p = par[c];
  const float4 y = *(const float4*)(y0 + i);
  const float4 xv = *(const float4*)(x + i);
  float4 r;
  r.x = y.x * p.x + p.y + xv.x;
  r.y = y.y * p.x + p.y + xv.y;
  r.z = y.z * p.x + p.y + xv.z;
  r.w = y.w * p.x + p.y + xv.w;
  *(float4*)(out + i) = r;
}

// ---------------------------------------------------------------------------
extern "C" void kernel_launch(void* const* d_in, const int* in_sizes, int n_in,
                              void* d_out, int out_size, void* d_ws, size_t ws_size,
                              hipStream_t stream)
{
  (void)in_sizes; (void)n_in; (void)out_size; (void)ws_size;
  const float* x   = (const float*)d_in[0];
  const float* qw  = (const float*)d_in[1];
  const float* kw  = (const float*)d_in[2];
  const float* vw  = (const float*)d_in[3];
  const float* vb  = (const float*)d_in[4];
  const float* gam = (const float*)d_in[5];
  const float* bnw = (const float*)d_in[6];
  const float* bnb = (const float*)d_in[7];

  char* ws = (char*)d_ws;
  f16*   qa  = (f16*)(ws);
  f16*   ka  = (f16*)(ws + (2u << 20));
  f16*   va  = (f16*)(ws + (4u << 20));
  float* y0  = (float*)(ws + (6u << 20));
  char*  st  = ws + (10u << 20);
  float*  gs1  = (float*)(st);           // 64 floats
  float*  gs2  = (float*)(st + 256);     // 64 floats
  float2* par  = (float2*)(st + 512);    // 64 float2

  hipMemsetAsync(st, 0, 512, stream);
  pam_pre  <<<256, 256, 0, stream>>>(x, qw, kw, vw, vb, qa, ka, va);
  pam_attn <<<512, 256, 0, stream>>>(qa, ka, va, gam, y0, gs1, gs2);
  pam_stats<<<1, 64, 0, stream>>>(gs1, gs2, bnw, bnb, par);
  pam_apply<<<1024, 256, 0, stream>>>(y0, x, par, (float*)d_out);
}

// Round 9
// 170.344 us; speedup vs baseline: 1.6224x; 1.1485x over previous
//
#include <hip/hip_runtime.h>
#include <stdint.h>

using f16 = _Float16;

typedef _Float16 f16x8 __attribute__((ext_vector_type(8)));
typedef float f32x4 __attribute__((ext_vector_type(4)));

#define LOG2E 1.44269504088896340736f

__device__ __forceinline__ f16 f2h(float f) { return (f16)f; }  // RNE

#if __has_builtin(__builtin_amdgcn_exp2f)
__device__ __forceinline__ float fexp2(float x) { return __builtin_amdgcn_exp2f(x); }
#else
__device__ __forceinline__ float fexp2(float x) { return exp2f(x); }
#endif

__device__ __forceinline__ f16x8 cvt8(const float* p) {
  const float4 a = *(const float4*)p;
  const float4 b = *(const float4*)(p + 4);
  f16x8 r;
  r[0] = (f16)a.x; r[1] = (f16)a.y; r[2] = (f16)a.z; r[3] = (f16)a.w;
  r[4] = (f16)b.x; r[5] = (f16)b.y; r[6] = (f16)b.z; r[7] = (f16)b.w;
  return r;
}

// B=4, C=64, N=4096.  Global in/out tensors FP32; internal tensor-core path FP16.
// ws layout (bytes):
//   0        qa  f16 [4][4096][64]  (2 MB)   q * log2e, position-major
//   2 MB     ka  f16 [4][4096][64]  (2 MB)
//   4 MB     va  f16 [4][64][4096]  (2 MB)   channel-major
//   6 MB     y0  f32 [4][64][4096]  (4 MB)   gamma*attn_out, pre-BN
//   10 MB    stats: gs1[64] | gs2[64] | par float2[64]

// ---------------------------------------------------------------------------
// pre: conv1d q/k over channels, v = vw@x+vb via MFMA
// ---------------------------------------------------------------------------
__global__ __launch_bounds__(256, 1) void pam_pre(
    const float* __restrict__ x, const float* __restrict__ qw,
    const float* __restrict__ kw, const float* __restrict__ vw,
    const float* __restrict__ vb,
    f16* __restrict__ qa, f16* __restrict__ ka, f16* __restrict__ va)
{
  __shared__ alignas(16) f16 xt[64 * 72];   // xt[n][c] f16, row stride 72 elems
  const int tid = threadIdx.x;
  const int b = blockIdx.x >> 6;
  const int n0 = (blockIdx.x & 63) << 6;
  const int lane = tid & 63;
  const int wv = tid >> 6;
  const int quad = lane >> 4, l15 = lane & 15;

  for (int p = 0; p < 4; ++p) {
    const int c = p * 16 + (tid >> 4);
    const int j0 = (tid & 15) << 2;
    const float4 v4 = *(const float4*)(x + ((size_t)(b * 64 + c) << 12) + n0 + j0);
    xt[(j0 + 0) * 72 + c] = f2h(v4.x);
    xt[(j0 + 1) * 72 + c] = f2h(v4.y);
    xt[(j0 + 2) * 72 + c] = f2h(v4.z);
    xt[(j0 + 3) * 72 + c] = f2h(v4.w);
  }
  __syncthreads();

  const float qw0 = qw[0], qw1 = qw[1], qw2 = qw[2];
  const float kw0 = kw[0], kw1 = kw[1], kw2 = kw[2];
  for (int p = 0; p < 16; ++p) {
    const int c = lane;
    const int jr = (p << 2) + wv;
    const int n = n0 + jr;
    const float xm = (c > 0) ? (float)xt[jr * 72 + c - 1] : 0.f;
    const float x0 = (float)xt[jr * 72 + c];
    const float xp = (c < 63) ? (float)xt[jr * 72 + c + 1] : 0.f;
    const float qv = (qw0 * xm + qw1 * x0 + qw2 * xp) * LOG2E;  // log2-domain
    const float kv = kw0 * xm + kw1 * x0 + kw2 * xp;
    const size_t off = ((size_t)((b << 12) + n) << 6) + c;
    qa[off] = f2h(qv);
    ka[off] = f2h(kv);
  }

  {
    const f16x8 a0 = cvt8(vw + (wv * 16 + l15) * 64 + quad * 8);
    const f16x8 a1 = cvt8(vw + (wv * 16 + l15) * 64 + quad * 8 + 32);
    f32x4 acc[4];
    for (int st = 0; st < 4; ++st) {
      const f16x8 b0 = *(const f16x8*)&xt[(st * 16 + l15) * 72 + quad * 8];
      const f16x8 b1 = *(const f16x8*)&xt[(st * 16 + l15) * 72 + quad * 8 + 32];
      f32x4 z = {0.f, 0.f, 0.f, 0.f};
      z = __builtin_amdgcn_mfma_f32_16x16x32_f16(a0, b0, z, 0, 0, 0);
      acc[st] = __builtin_amdgcn_mfma_f32_16x16x32_f16(a1, b1, z, 0, 0, 0);
    }
    const int cobase = wv * 16 + quad * 4;
    for (int st = 0; st < 4; ++st)
      for (int r = 0; r < 4; ++r) {
        const int co = cobase + r;
        const float val = acc[st][r] + vb[co];
        va[((size_t)(b * 64 + co) << 12) + n0 + st * 16 + l15] = f2h(val);
      }
  }
}

// ---------------------------------------------------------------------------
// attention: block = (b, 32 queries = 2 q-tiles); 4 waves key-split (32 keys
// each, KT=128). SINGLE PASS, online softmax. 1-deep register prefetch.
// m/l in S^T layout (query=l15, quad-uniform); lpart is a PER-LANE partial
// over that lane's 8 keys -> MUST be cross-quad reduced before publish
// (r8 bug: published quad-0 partial -> l ~4x small, non-uniform -> absmax 126).
// alpha redistributed to C-layout (query=quad*4+r) via shfl; cross-wave merge
// is m-aware. Per-block phase rotation decorrelates L2 streams (anti-convoy).
// ---------------------------------------------------------------------------
__global__ __launch_bounds__(256, 2) void pam_attn(
    const f16* __restrict__ qa, const f16* __restrict__ ka,
    const f16* __restrict__ va, const float* __restrict__ gam,
    float* __restrict__ y0, float* __restrict__ gs1, float* __restrict__ gs2)
{
  __shared__ alignas(16) f16 pbuf[4][32 * 32];  // per-wave P, 64B rows, 16B-chunk xor swizzle
  __shared__ float ldsO[32 * 65];
  __shared__ float ldsL[4][32];
  __shared__ float ldsM[4][32];
  __shared__ float ldsInv[32];

  const int tid = threadIdx.x;
  const int wv = tid >> 6, lane = tid & 63;
  const int quad = lane >> 4, l15 = lane & 15;
  const int b = blockIdx.x & 3;
  const int qt_idx = blockIdx.x >> 2;          // 0..127
  const int qb0 = qt_idx << 5;
  const int phase = qt_idx & 31;               // anti-convoy rotation

  for (int i = tid; i < 32 * 65; i += 256) ldsO[i] = 0.f;

  const int bn = b << 12;
  f16x8 bq[2][2];
  for (int qt = 0; qt < 2; ++qt) {
    const int q = qb0 + qt * 16 + l15;
    const f16* qp = qa + ((size_t)(bn + q) << 6) + quad * 8;
    bq[qt][0] = *(const f16x8*)qp;
    bq[qt][1] = *(const f16x8*)(qp + 32);
  }

  f32x4 o[2][4] = {};
  float m[2] = {-1e30f, -1e30f};
  float lpart[2] = {0.f, 0.f};
  f16* pb = pbuf[wv];

  // preload iteration 0 K/V fragments
  f16x8 ak[2][2], bv[4];
  {
    const int kb = (phase << 7) + wv * 32;
    for (int mt = 0; mt < 2; ++mt) {
      const f16* kp = ka + ((size_t)(bn + kb + mt * 16 + l15) << 6) + quad * 8;
      ak[mt][0] = *(const f16x8*)kp;
      ak[mt][1] = *(const f16x8*)(kp + 32);
    }
    for (int ct = 0; ct < 4; ++ct)
      bv[ct] = *(const f16x8*)(va + ((size_t)(b * 64 + ct * 16 + l15) << 12) + kb + quad * 8);
  }

#pragma unroll 1
  for (int kt = 0; kt < 32; ++kt) {
    // prefetch next iteration's K/V into separate regs (wraps at 32)
    f16x8 akn[2][2], bvn[4];
    {
      const int kb2 = ((((kt + 1) + phase) & 31) << 7) + wv * 32;
      for (int mt = 0; mt < 2; ++mt) {
        const f16* kp = ka + ((size_t)(bn + kb2 + mt * 16 + l15) << 6) + quad * 8;
        akn[mt][0] = *(const f16x8*)kp;
        akn[mt][1] = *(const f16x8*)(kp + 32);
      }
      for (int ct = 0; ct < 4; ++ct)
        bvn[ct] = *(const f16x8*)(va + ((size_t)(b * 64 + ct * 16 + l15) << 12) + kb2 + quad * 8);
    }

    // S^T = K_slice * Q^T (C=0); online max/rescale; P -> LDS; PV
    for (int qt = 0; qt < 2; ++qt) {
      f32x4 s[2];
      for (int mt = 0; mt < 2; ++mt) {
        f32x4 z = {0.f, 0.f, 0.f, 0.f};
        z = __builtin_amdgcn_mfma_f32_16x16x32_f16(ak[mt][0], bq[qt][0], z, 0, 0, 0);
        s[mt] = __builtin_amdgcn_mfma_f32_16x16x32_f16(ak[mt][1], bq[qt][1], z, 0, 0, 0);
      }
      // tile max for this query (col=l15) across this wave's 32 keys
      float tmax = fmaxf(fmaxf(fmaxf(s[0][0], s[0][1]), fmaxf(s[0][2], s[0][3])),
                         fmaxf(fmaxf(s[1][0], s[1][1]), fmaxf(s[1][2], s[1][3])));
      tmax = fmaxf(tmax, __shfl_xor(tmax, 16, 64));
      tmax = fmaxf(tmax, __shfl_xor(tmax, 32, 64));
      const float mnew = fmaxf(m[qt], tmax);
      const float alpha = fexp2(m[qt] - mnew);   // (l15 = query) layout, quad-uniform
      m[qt] = mnew;

      // P = exp2(S - mnew); update per-lane partial l; pack -> LDS (swizzled)
      const int rowq = qt * 16 + l15;
      char* rowp = (char*)pb + rowq * 64;
      const int sw = rowq & 3;
      float tsum = 0.f;
      for (int mt = 0; mt < 2; ++mt) {
        const float p0 = fexp2(s[mt][0] - mnew);
        const float p1 = fexp2(s[mt][1] - mnew);
        const float p2 = fexp2(s[mt][2] - mnew);
        const float p3 = fexp2(s[mt][3] - mnew);
        tsum += (p0 + p1) + (p2 + p3);
        union { f16 h[4]; uint2 u; } pk;
        pk.h[0] = f2h(p0); pk.h[1] = f2h(p1);
        pk.h[2] = f2h(p2); pk.h[3] = f2h(p3);
        const int cc = (2 * mt + (quad >> 1)) ^ sw;
        *(uint2*)(rowp + cc * 16 + (quad & 1) * 8) = pk.u;
      }
      lpart[qt] = lpart[qt] * alpha + tsum;   // per-lane partial (8 keys/lane)

      // rescale o: o-queries are quad*4+r -> fetch alpha from lane (quad<<4)|(quad*4+r)
      const int srcbase = (lane & 48) + ((lane >> 4) << 2);
      for (int r = 0; r < 4; ++r) {
        const float ar = __shfl(alpha, srcbase + r, 64);
        for (int ct = 0; ct < 4; ++ct) o[qt][ct][r] *= ar;
      }
    }
    __builtin_amdgcn_s_waitcnt(0xC07F);  // lgkmcnt(0): per-wave P writes visible

    // O += P * V
    for (int qt = 0; qt < 2; ++qt) {
      const int rowq = qt * 16 + l15;
      const f16x8 ap =
          *(const f16x8*)((const char*)pb + rowq * 64 + ((quad ^ (rowq & 3)) << 4));
      for (int ct = 0; ct < 4; ++ct)
        o[qt][ct] = __builtin_amdgcn_mfma_f32_16x16x32_f16(ap, bv[ct], o[qt][ct], 0, 0, 0);
    }

    for (int mt = 0; mt < 2; ++mt) { ak[mt][0] = akn[mt][0]; ak[mt][1] = akn[mt][1]; }
    for (int ct = 0; ct < 4; ++ct) bv[ct] = bvn[ct];
  }

  // publish per-wave online state: m is quad-uniform; lpart is a PER-LANE
  // partial and must be reduced across quads first (the r8 bug).
  for (int qt = 0; qt < 2; ++qt) {
    float v = lpart[qt];
    v += __shfl_xor(v, 16, 64);
    v += __shfl_xor(v, 32, 64);
    if (quad == 0) {
      ldsM[wv][qt * 16 + l15] = m[qt];
      ldsL[wv][qt * 16 + l15] = v;
    }
  }
  __syncthreads();  // ldsM/ldsL published; ldsO zero-init complete

  // m-aware merge of partial O across the 4 key-split waves
  for (int qt = 0; qt < 2; ++qt) {
    for (int r = 0; r < 4; ++r) {
      const int q = qt * 16 + quad * 4 + r;
      const float M = fmaxf(fmaxf(ldsM[0][q], ldsM[1][q]),
                            fmaxf(ldsM[2][q], ldsM[3][q]));
      const float sc = fexp2(ldsM[wv][q] - M);
      for (int ct = 0; ct < 4; ++ct)
        atomicAdd(&ldsO[q * 65 + ct * 16 + l15], o[qt][ct][r] * sc);
    }
  }
  __syncthreads();
  if (tid < 32) {
    const int q = tid;
    const float M = fmaxf(fmaxf(ldsM[0][q], ldsM[1][q]),
                          fmaxf(ldsM[2][q], ldsM[3][q]));
    const float lt = ldsL[0][q] * fexp2(ldsM[0][q] - M) +
                     ldsL[1][q] * fexp2(ldsM[1][q] - M) +
                     ldsL[2][q] * fexp2(ldsM[2][q] - M) +
                     ldsL[3][q] * fexp2(ldsM[3][q] - M);
    ldsInv[q] = 1.f / lt;
  }
  __syncthreads();

  // epilogue: y0[b][c][n] = gamma * O / l ; BN partial sums
  const float g = gam[0];
  {
    const int c = tid >> 2;
    const int q0 = (tid & 3) << 3;
    float s1 = 0.f, s2 = 0.f;
    float4 v4a, v4b;
    float* va4 = &v4a.x;
    float* vb4 = &v4b.x;
    for (int r = 0; r < 4; ++r) {
      const float val = g * ldsO[(q0 + r) * 65 + c] * ldsInv[q0 + r];
      va4[r] = val; s1 += val; s2 += val * val;
    }
    for (int r = 0; r < 4; ++r) {
      const float val = g * ldsO[(q0 + 4 + r) * 65 + c] * ldsInv[q0 + 4 + r];
      vb4[r] = val; s1 += val; s2 += val * val;
    }
    float* dst = y0 + ((size_t)(b * 64 + c) << 12) + qb0 + q0;
    *(float4*)dst = v4a;
    *(float4*)(dst + 4) = v4b;
    s1 += __shfl_xor(s1, 1, 64);
    s2 += __shfl_xor(s2, 1, 64);
    s1 += __shfl_xor(s1, 2, 64);
    s2 += __shfl_xor(s2, 2, 64);
    if ((tid & 3) == 0) {
      atomicAdd(&gs1[c], s1);
      atomicAdd(&gs2[c], s2);
    }
  }
}

// ---------------------------------------------------------------------------
__global__ __launch_bounds__(64, 1) void pam_stats(
    const float* __restrict__ gs1, const float* __restrict__ gs2,
    const float* __restrict__ bnw, const float* __restrict__ bnb,
    float2* __restrict__ par)
{
  const int c = threadIdx.x;
  const float inv_n = 1.f / 16384.f;
  const float mean = gs1[c] * inv_n;
  const float var = fmaxf(gs2[c] * inv_n - mean * mean, 0.f);
  const float sc = bnw[c] * rsqrtf(var + 1e-5f);
  par[c] = make_float2(sc, bnb[c] - mean * sc);
}

// ---------------------------------------------------------------------------
__global__ __launch_bounds__(256, 1) void pam_apply(
    const float* __restrict__ y0, const float* __restrict__ x,
    const float2* __restrict__ par, float* __restrict__ out)
{
  const int i = (blockIdx.x * 256 + threadIdx.x) << 2;   // 4 elems/thread, exact cover
  const int c = (i >> 12) & 63;
  const float2 p = par[c];
  const float4 y = *(const float4*)(y0 + i);
  const float4 xv = *(const float4*)(x + i);
  float4 r;
  r.x = y.x * p.x + p.y + xv.x;
  r.y = y.y * p.x + p.y + xv.y;
  r.z = y.z * p.x + p.y + xv.z;
  r.w = y.w * p.x + p.y + xv.w;
  *(float4*)(out + i) = r;
}

// ---------------------------------------------------------------------------
extern "C" void kernel_launch(void* const* d_in, const int* in_sizes, int n_in,
                              void* d_out, int out_size, void* d_ws, size_t ws_size,
                              hipStream_t stream)
{
  (void)in_sizes; (void)n_in; (void)out_size; (void)ws_size;
  const float* x   = (const float*)d_in[0];
  const float* qw  = (const float*)d_in[1];
  const float* kw  = (const float*)d_in[2];
  const float* vw  = (const float*)d_in[3];
  const float* vb  = (const float*)d_in[4];
  const float* gam = (const float*)d_in[5];
  const float* bnw = (const float*)d_in[6];
  const float* bnb = (const float*)d_in[7];

  char* ws = (char*)d_ws;
  f16*   qa  = (f16*)(ws);
  f16*   ka  = (f16*)(ws + (2u << 20));
  f16*   va  = (f16*)(ws + (4u << 20));
  float* y0  = (float*)(ws + (6u << 20));
  char*  st  = ws + (10u << 20);
  float*  gs1  = (float*)(st);           // 64 floats
  float*  gs2  = (float*)(st + 256);     // 64 floats
  float2* par  = (float2*)(st + 512);    // 64 float2

  hipMemsetAsync(st, 0, 512, stream);
  pam_pre  <<<256, 256, 0, stream>>>(x, qw, kw, vw, vb, qa, ka, va);
  pam_attn <<<512, 256, 0, stream>>>(qa, ka, va, gam, y0, gs1, gs2);
  pam_stats<<<1, 64, 0, stream>>>(gs1, gs2, bnw, bnb, par);
  pam_apply<<<1024, 256, 0, stream>>>(y0, x, par, (float*)d_out);
}